// Round 4
// baseline (298.025 us; speedup 1.0000x reference)
//
#include <hip/hip_runtime.h>
#include <stdint.h>

// ---------- types / helpers ----------
typedef __attribute__((ext_vector_type(8))) short short8;   // 8 x bf16 bits
typedef __attribute__((ext_vector_type(4))) float f32x4;

__device__ __forceinline__ unsigned short f2bf(float f) {
  unsigned u = __float_as_uint(f);
  u += 0x7fffu + ((u >> 16) & 1u);           // round-to-nearest-even
  return (unsigned short)(u >> 16);
}
__device__ __forceinline__ float bf2f(unsigned short u) {
  return __uint_as_float(((unsigned)u) << 16);
}

#define GLDS16(gp, lp)                                              \
  __builtin_amdgcn_global_load_lds(                                  \
      (const __attribute__((address_space(1))) void*)(gp),           \
      (__attribute__((address_space(3))) void*)(lp), 16, 0, 0)

// ---------- kernel 1: cast h (f32) -> hA (bf16) ----------
__global__ void __launch_bounds__(256) cast_h_kernel(const float* __restrict__ h,
                                                     unsigned short* __restrict__ hA,
                                                     long long total8) {
  long long i = (long long)blockIdx.x * 256 + threadIdx.x;
  if (i >= total8) return;
  const float4* p = (const float4*)(h + i * 8);
  float4 f0 = p[0], f1 = p[1];
  short8 r;
  r[0] = (short)f2bf(f0.x); r[1] = (short)f2bf(f0.y);
  r[2] = (short)f2bf(f0.z); r[3] = (short)f2bf(f0.w);
  r[4] = (short)f2bf(f1.x); r[5] = (short)f2bf(f1.y);
  r[6] = (short)f2bf(f1.z); r[7] = (short)f2bf(f1.w);
  *(short8*)(hA + i * 8) = r;
}

// ---------- kernel 2: BT[n][k] = bf16(W1[(n>=512? 512:0)+k][n&511]) ----------
__global__ void __launch_bounds__(256) buildBT_kernel(const float* __restrict__ W1,
                                                      unsigned short* __restrict__ BT) {
  int t = blockIdx.x * 256 + threadIdx.x;   // 0..524287
  int n = t >> 9;
  int k = t & 511;
  float v = W1[((size_t)((n >> 9) * 512 + k)) * 512 + (size_t)(n & 511)];
  BT[t] = f2bf(v);
}

// ---------- kernel 3: GEMM  P[M][1024](bf16) = hA[M][512] @ BT^T (+b1 cols<512) ----------
// 128x128 tile, BK=64, 256 threads (4 waves, 64x64/wave), DOUBLE-BUFFERED LDS with
// COUNTED vmcnt(8) + raw s_barrier (T4): next-tile loads stay in flight across the
// barrier; no vmcnt(0) drain inside the main loop.
__global__ void __launch_bounds__(256) gemm_kernel(const unsigned short* __restrict__ hA,
                                                   const unsigned short* __restrict__ BT,
                                                   const float* __restrict__ b1,
                                                   unsigned short* __restrict__ P,
                                                   int M) {
  __shared__ unsigned short As[2][128 * 64];   // 2 x 16 KB
  __shared__ unsigned short Bs[2][128 * 64];   // 2 x 16 KB

  // --- XCD-chunked block swizzle; logical order: n-tile fastest within an A strip ---
  const int nwg = gridDim.x;                // Mtiles*8, divisible by 8
  const int cpx = nwg >> 3;
  const int wg  = (blockIdx.x & 7) * cpx + (blockIdx.x >> 3);
  const int nt  = wg & 7;
  const int mt  = wg >> 3;
  const int m0  = mt * 128;
  const int n0  = nt * 128;

  const int tid  = threadIdx.x;
  const int lane = tid & 63;
  const int wid  = tid >> 6;
  const int wr   = wid >> 1, wc = wid & 1;

  f32x4 acc[4][4];
#pragma unroll
  for (int i = 0; i < 4; ++i)
#pragma unroll
    for (int j = 0; j < 4; ++j) acc[i][j] = (f32x4){0.f, 0.f, 0.f, 0.f};

  const int srow = tid >> 3;     // 0..31 (q adds +32)
  const int slot = tid & 7;      // 16B slot within 128B row

  const int lr = lane & 15;
  const int g  = lane >> 4;      // 0..3

  // Exactly 8 global_load_lds per thread per STAGE (row CLAMPED, never skipped,
  // so per-wave vmcnt bookkeeping is exact).
#define STAGE(buf, kt)                                                          \
  {                                                                             \
    const int k0_ = (kt) * 64;                                                  \
    _Pragma("unroll")                                                           \
    for (int q = 0; q < 4; ++q) {                                               \
      const int row_ = q * 32 + srow;                                           \
      const int gk_  = k0_ + ((slot ^ (row_ & 7)) << 3);                        \
      int ga_ = m0 + row_; ga_ = (ga_ < M) ? ga_ : (M - 1);                     \
      GLDS16(hA + (size_t)ga_ * 512 + gk_, &As[buf][row_ * 64 + slot * 8]);     \
      GLDS16(BT + (size_t)(n0 + row_) * 512 + gk_, &Bs[buf][row_ * 64 + slot * 8]); \
    }                                                                           \
  }

  STAGE(0, 0);                   // 8 loads in flight

  int cur = 0;
#pragma unroll 1
  for (int kt = 0; kt < 8; ++kt) {
    if (kt < 7) {
      STAGE(cur ^ 1, kt + 1);                               // +8 loads (16 in flight)
      asm volatile("s_waitcnt vmcnt(8)" ::: "memory");      // oldest 8 (= buf[cur]) done
    } else {
      asm volatile("s_waitcnt vmcnt(0)" ::: "memory");
    }
    __builtin_amdgcn_s_barrier();            // all waves staged buf[cur]
    __builtin_amdgcn_sched_barrier(0);       // no ds_read hoists above this point

    short8 aF[2][4], bF[2][4];
#pragma unroll
    for (int s = 0; s < 2; ++s) {
#pragma unroll
      for (int i = 0; i < 4; ++i) {
        const int row = wr * 64 + i * 16 + lr;
        const int p   = (s * 4 + g) ^ (row & 7);
        aF[s][i] = *(const short8*)&As[cur][row * 64 + p * 8];
      }
#pragma unroll
      for (int j = 0; j < 4; ++j) {
        const int row = wc * 64 + j * 16 + lr;
        const int p   = (s * 4 + g) ^ (row & 7);
        bF[s][j] = *(const short8*)&Bs[cur][row * 64 + p * 8];
      }
    }
#pragma unroll
    for (int s = 0; s < 2; ++s)
#pragma unroll
      for (int i = 0; i < 4; ++i)
#pragma unroll
        for (int j = 0; j < 4; ++j)
          acc[i][j] = __builtin_amdgcn_mfma_f32_16x16x32_bf16(aF[s][i], bF[s][j], acc[i][j], 0, 0, 0);

    asm volatile("s_waitcnt lgkmcnt(0)" ::: "memory");  // my reads of buf[cur] complete
    __builtin_amdgcn_sched_barrier(0);
    __builtin_amdgcn_s_barrier();            // now next iter may overwrite buf[cur]
    cur ^= 1;
  }
#undef STAGE

  // --- epilogue: bias + bf16 + LDS repack for coalesced stores ---
  float bias[4];
#pragma unroll
  for (int j = 0; j < 4; ++j) {
    const int col = n0 + wc * 64 + j * 16 + lr;
    bias[j] = (col < 512) ? b1[col] : 0.0f;
  }
  unsigned short* Ls = &As[0][0];        // 32 x 128 bf16 = 8 KB, reuse
  const int lrow2 = tid >> 3;            // 0..31
  const int c0    = (tid & 7) * 16;      // 16 elems = 32B per thread
  const int grB   = m0 + (lrow2 >> 4) * 64;
#pragma unroll
  for (int i = 0; i < 4; ++i) {
#pragma unroll
    for (int j = 0; j < 4; ++j) {
      const int col  = wc * 64 + j * 16 + lr;
      const int lrow = wr * 16 + g * 4;
#pragma unroll
      for (int r = 0; r < 4; ++r)
        Ls[(lrow + r) * 128 + col] = f2bf(acc[i][j][r] + bias[j]);
    }
    __syncthreads();
    const int gr = grB + i * 16 + (lrow2 & 15);
    if (gr < M) {
      const short8 v0 = *(const short8*)&Ls[lrow2 * 128 + c0];
      const short8 v1 = *(const short8*)&Ls[lrow2 * 128 + c0 + 8];
      *(short8*)(P + (size_t)gr * 1024 + n0 + c0)     = v0;
      *(short8*)(P + (size_t)gr * 1024 + n0 + c0 + 8) = v1;
    }
    __syncthreads();
  }
}

// ---------- kernel 4: per-edge score ----------
__global__ void __launch_bounds__(256) edge_kernel(const unsigned short* __restrict__ P,
                                                   const int* __restrict__ src,
                                                   const int* __restrict__ dst,
                                                   const float* __restrict__ W2,
                                                   const float* __restrict__ b2,
                                                   float* __restrict__ out,
                                                   int E) {
  const int gw   = (blockIdx.x * 256 + threadIdx.x) >> 6;   // global wave = edge
  const int lane = threadIdx.x & 63;
  if (gw >= E) return;
  const int s = src[gw];
  const int d = dst[gw];
  const short8 va = *(const short8*)(P + (size_t)s * 1024 + lane * 8);
  const short8 vb = *(const short8*)(P + (size_t)d * 1024 + 512 + lane * 8);
  const float4 w0 = *(const float4*)(W2 + lane * 8);
  const float4 w1 = *(const float4*)(W2 + lane * 8 + 4);
  float a = 0.f, x;
  x = bf2f((unsigned short)va[0]) + bf2f((unsigned short)vb[0]); a += fmaxf(x, 0.f) * w0.x;
  x = bf2f((unsigned short)va[1]) + bf2f((unsigned short)vb[1]); a += fmaxf(x, 0.f) * w0.y;
  x = bf2f((unsigned short)va[2]) + bf2f((unsigned short)vb[2]); a += fmaxf(x, 0.f) * w0.z;
  x = bf2f((unsigned short)va[3]) + bf2f((unsigned short)vb[3]); a += fmaxf(x, 0.f) * w0.w;
  x = bf2f((unsigned short)va[4]) + bf2f((unsigned short)vb[4]); a += fmaxf(x, 0.f) * w1.x;
  x = bf2f((unsigned short)va[5]) + bf2f((unsigned short)vb[5]); a += fmaxf(x, 0.f) * w1.y;
  x = bf2f((unsigned short)va[6]) + bf2f((unsigned short)vb[6]); a += fmaxf(x, 0.f) * w1.z;
  x = bf2f((unsigned short)va[7]) + bf2f((unsigned short)vb[7]); a += fmaxf(x, 0.f) * w1.w;
#pragma unroll
  for (int o = 32; o > 0; o >>= 1) a += __shfl_down(a, o);
  if (lane == 0) out[gw] = a + b2[0];
}

// ---------- launcher ----------
extern "C" void kernel_launch(void* const* d_in, const int* in_sizes, int n_in,
                              void* d_out, int out_size, void* d_ws, size_t ws_size,
                              hipStream_t stream) {
  const float* h  = (const float*)d_in[0];
  const int*   src = (const int*)d_in[1];
  const int*   dst = (const int*)d_in[2];
  const float* W1 = (const float*)d_in[3];
  const float* b1 = (const float*)d_in[4];
  const float* W2 = (const float*)d_in[5];
  const float* b2 = (const float*)d_in[6];
  float* out = (float*)d_out;

  const int M = in_sizes[0] / 512;   // 100000 nodes
  const int E = in_sizes[1];         // 160000 edges

  char* ws = (char*)d_ws;
  unsigned short* hA = (unsigned short*)ws;                          // M*512 bf16
  size_t off = (((size_t)M * 512 * 2) + 255) & ~(size_t)255;
  unsigned short* BT = (unsigned short*)(ws + off);                  // 1024*512 bf16
  off += (size_t)1024 * 512 * 2;
  unsigned short* P = (unsigned short*)(ws + off);                   // M*1024 bf16

  const long long total8 = (long long)M * 512 / 8;
  cast_h_kernel<<<(int)((total8 + 255) / 256), 256, 0, stream>>>(h, hA, total8);
  buildBT_kernel<<<2048, 256, 0, stream>>>(W1, BT);
  const int Mtiles = (M + 127) / 128;
  gemm_kernel<<<Mtiles * 8, 256, 0, stream>>>(hA, BT, b1, P, M);
  edge_kernel<<<(E + 3) / 4, 256, 0, stream>>>(P, src, dst, W2, b2, out, E);
}

// Round 5
// 259.849 us; speedup vs baseline: 1.1469x; 1.1469x over previous
//
#include <hip/hip_runtime.h>
#include <stdint.h>

// ---------- types / helpers ----------
typedef __attribute__((ext_vector_type(8))) short short8;   // 8 x bf16 bits
typedef __attribute__((ext_vector_type(4))) float f32x4;

__device__ __forceinline__ unsigned short f2bf(float f) {
  unsigned u = __float_as_uint(f);
  u += 0x7fffu + ((u >> 16) & 1u);           // round-to-nearest-even
  return (unsigned short)(u >> 16);
}
__device__ __forceinline__ float bf2f(unsigned short u) {
  return __uint_as_float(((unsigned)u) << 16);
}

#define GLDS16(gp, lp)                                              \
  __builtin_amdgcn_global_load_lds(                                  \
      (const __attribute__((address_space(1))) void*)(gp),           \
      (__attribute__((address_space(3))) void*)(lp), 16, 0, 0)

// ---------- kernel 1: cast h (f32) -> hA (bf16) ----------
__global__ void __launch_bounds__(256) cast_h_kernel(const float* __restrict__ h,
                                                     unsigned short* __restrict__ hA,
                                                     long long total8) {
  long long i = (long long)blockIdx.x * 256 + threadIdx.x;
  if (i >= total8) return;
  const float4* p = (const float4*)(h + i * 8);
  float4 f0 = p[0], f1 = p[1];
  short8 r;
  r[0] = (short)f2bf(f0.x); r[1] = (short)f2bf(f0.y);
  r[2] = (short)f2bf(f0.z); r[3] = (short)f2bf(f0.w);
  r[4] = (short)f2bf(f1.x); r[5] = (short)f2bf(f1.y);
  r[6] = (short)f2bf(f1.z); r[7] = (short)f2bf(f1.w);
  *(short8*)(hA + i * 8) = r;
}

// ---------- kernel 2: BT[n][k] = bf16(W1[(n>=512? 512:0)+k][n&511]) ----------
__global__ void __launch_bounds__(256) buildBT_kernel(const float* __restrict__ W1,
                                                      unsigned short* __restrict__ BT) {
  int t = blockIdx.x * 256 + threadIdx.x;   // 0..524287
  int n = t >> 9;
  int k = t & 511;
  float v = W1[((size_t)((n >> 9) * 512 + k)) * 512 + (size_t)(n & 511)];
  BT[t] = f2bf(v);
}

// ---------- kernel 3: 256x256 8-phase GEMM (T3+T4+T5), BK=64, 8 waves ----------
// P[M][1024](bf16) = hA[M][512] @ BT^T (+b1 cols<512)
// Half-tiles (16KB) staged order [A0,B0,B1,A1] per k-tile; stage ptr h=7+4t+p;
// ONE boundary s_waitcnt vmcnt(6) per k-tile; 2 barriers/phase; setprio around MFMA.
__global__ void __launch_bounds__(512, 2) gemm_kernel(const unsigned short* __restrict__ hA,
                                                      const unsigned short* __restrict__ BT,
                                                      const float* __restrict__ b1,
                                                      unsigned short* __restrict__ P,
                                                      int M) {
  __shared__ unsigned short Al[2][256 * 64];   // 64 KB (dbuf)
  __shared__ unsigned short Bl[2][256 * 64];   // 64 KB

  // --- bijective XCD-chunked swizzle (m204), n-tile fastest within chunk ---
  const int nwg = gridDim.x;
  const int q8 = nwg >> 3, r8 = nwg & 7;
  const int xcd = blockIdx.x & 7;
  const int lin = blockIdx.x >> 3;
  const int wgid = (xcd < r8 ? xcd * (q8 + 1) : r8 * (q8 + 1) + (xcd - r8) * q8) + lin;
  const int mt = wgid >> 2;          // Ntiles = 4
  const int nt = wgid & 3;
  const int m0 = mt * 256, n0 = nt * 256;

  const int tid  = threadIdx.x;
  const int lane = tid & 63;
  const int wid  = tid >> 6;         // 0..7
  const int wr   = wid >> 2;         // 0..1 (M)
  const int wc   = wid & 3;          // 0..3 (N)
  const int lr   = lane & 15;
  const int g    = lane >> 4;        // 0..3

  // --- staging precompute (thread-constant) ---
  const int r0 = tid >> 3;           // 0..63
  const int s8 = tid & 7;
  const unsigned swk = (unsigned)((s8 ^ (r0 & 7)) << 3);   // swizzled k-slot (elems)
  int ga0 = m0 + r0;        ga0 = ga0 < M ? ga0 : M - 1;
  int ga1 = m0 + r0 + 64;   ga1 = ga1 < M ? ga1 : M - 1;
  int ga2 = m0 + r0 + 128;  ga2 = ga2 < M ? ga2 : M - 1;
  int ga3 = m0 + r0 + 192;  ga3 = ga3 < M ? ga3 : M - 1;
  const unsigned aOff0 = (unsigned)ga0 * 512u, aOff1 = (unsigned)ga1 * 512u;
  const unsigned aOff2 = (unsigned)ga2 * 512u, aOff3 = (unsigned)ga3 * 512u;
  const unsigned bOff0 = (unsigned)(n0 + r0) * 512u;
  const unsigned bOff1 = (unsigned)(n0 + r0 + 64) * 512u;
  const unsigned bOff2 = (unsigned)(n0 + r0 + 128) * 512u;
  const unsigned bOff3 = (unsigned)(n0 + r0 + 192) * 512u;
  const unsigned ldsO0 = (unsigned)(r0 * 64 + s8 * 8);
  const unsigned ldsO1 = ldsO0 + 64u * 64u;
  const unsigned ldsO2 = ldsO0 + 128u * 64u;
  const unsigned ldsO3 = ldsO0 + 192u * 64u;

#define STAGE_HT(h)                                                          \
  if ((h) < 32) {                                                            \
    const int kt_ = (h) >> 2, j_ = (h) & 3, sl_ = kt_ & 1;                   \
    const unsigned kc_ = (unsigned)kt_ * 64u + swk;                          \
    unsigned short* Ab_ = &Al[sl_][0];                                       \
    unsigned short* Bb_ = &Bl[sl_][0];                                       \
    switch (j_) {                                                            \
      case 0: GLDS16(hA + aOff0 + kc_, Ab_ + ldsO0);                         \
              GLDS16(hA + aOff1 + kc_, Ab_ + ldsO1); break;                  \
      case 1: GLDS16(BT + bOff0 + kc_, Bb_ + ldsO0);                         \
              GLDS16(BT + bOff1 + kc_, Bb_ + ldsO1); break;                  \
      case 2: GLDS16(BT + bOff2 + kc_, Bb_ + ldsO2);                         \
              GLDS16(BT + bOff3 + kc_, Bb_ + ldsO3); break;                  \
      default: GLDS16(hA + aOff2 + kc_, Ab_ + ldsO2);                        \
               GLDS16(hA + aOff3 + kc_, Ab_ + ldsO3); break;                 \
    }                                                                        \
  }

  // --- accumulators / fragments ---
  f32x4 acc[8][4];
#pragma unroll
  for (int i = 0; i < 8; ++i)
#pragma unroll
    for (int j = 0; j < 4; ++j) acc[i][j] = (f32x4){0.f, 0.f, 0.f, 0.f};
  short8 aF[2][4], bF[2][4];

  const unsigned x7   = (unsigned)(lr & 7);
  const unsigned c0   = (unsigned)(((0u * 4u + g) ^ x7) << 3);   // ks=0 chunk (elems)
  const unsigned c1   = (unsigned)(((1u * 4u + g) ^ x7) << 3);   // ks=1
  const unsigned arow = (unsigned)(wr * 64 + lr);
  const unsigned bcol = (unsigned)(wc * 32 + lr);

#define RD_A(MIH)                                                      \
  _Pragma("unroll") for (int i = 0; i < 4; ++i) {                      \
    const unsigned rr = ((MIH) * 128u + arow + (unsigned)i * 16u) * 64u; \
    aF[0][i] = *(const short8*)(A_ + rr + c0);                         \
    aF[1][i] = *(const short8*)(A_ + rr + c1);                         \
  }
#define RD_B(NIH)                                                      \
  _Pragma("unroll") for (int n = 0; n < 2; ++n) {                      \
    const unsigned rr = ((NIH) * 128u + bcol + (unsigned)n * 16u) * 64u; \
    bF[0][(NIH) * 2 + n] = *(const short8*)(B_ + rr + c0);             \
    bF[1][(NIH) * 2 + n] = *(const short8*)(B_ + rr + c1);             \
  }
#define QUAD(MIH, NIH)                                                 \
  _Pragma("unroll") for (int ks = 0; ks < 2; ++ks)                     \
  _Pragma("unroll") for (int i = 0; i < 4; ++i)                        \
  _Pragma("unroll") for (int n = 0; n < 2; ++n)                        \
    acc[(MIH) * 4 + i][(NIH) * 2 + n] =                                \
        __builtin_amdgcn_mfma_f32_16x16x32_bf16(                       \
            aF[ks][i], bF[ks][(NIH) * 2 + n],                          \
            acc[(MIH) * 4 + i][(NIH) * 2 + n], 0, 0, 0);

  // --- prologue: stage 7 half-tiles (k0 full + k1 A0,B0,B1), wait k0 ---
  STAGE_HT(0) STAGE_HT(1) STAGE_HT(2) STAGE_HT(3) STAGE_HT(4) STAGE_HT(5) STAGE_HT(6)
  asm volatile("s_waitcnt vmcnt(6)" ::: "memory");
  __builtin_amdgcn_s_barrier();

  // --- main loop: 8 k-tiles x 4 phases ---
#pragma unroll 1
  for (int t = 0; t < 8; ++t) {
    const int sl = t & 1;
    const unsigned short* A_ = &Al[sl][0];
    const unsigned short* B_ = &Bl[sl][0];
    const int hb = 7 + 4 * t;

    // p0: A-half0 + B-half0 reads; stage A1 of t+1; MFMA (m0,n0)
    RD_A(0) RD_B(0) STAGE_HT(hb + 0)
    __builtin_amdgcn_s_barrier();
    __builtin_amdgcn_s_setprio(1); QUAD(0, 0) __builtin_amdgcn_s_setprio(0);
    __builtin_amdgcn_s_barrier();

    // p1: B-half1 reads; stage A0 of t+2; MFMA (m0,n1)
    RD_B(1) STAGE_HT(hb + 1)
    __builtin_amdgcn_s_barrier();
    __builtin_amdgcn_s_setprio(1); QUAD(0, 1) __builtin_amdgcn_s_setprio(0);
    __builtin_amdgcn_s_barrier();

    // p2: A-half1 reads; stage B0 of t+2; MFMA (m1,n1)
    RD_A(1) STAGE_HT(hb + 2)
    __builtin_amdgcn_s_barrier();
    __builtin_amdgcn_s_setprio(1); QUAD(1, 1) __builtin_amdgcn_s_setprio(0);
    __builtin_amdgcn_s_barrier();

    // p3: no reads; stage B1 of t+2; MFMA (m1,n0); k-tile boundary wait
    STAGE_HT(hb + 3)
    __builtin_amdgcn_s_barrier();
    __builtin_amdgcn_s_setprio(1); QUAD(1, 0) __builtin_amdgcn_s_setprio(0);
    if (t < 6)       { asm volatile("s_waitcnt vmcnt(6)" ::: "memory"); }
    else if (t == 6) { asm volatile("s_waitcnt vmcnt(0)" ::: "memory"); }
    __builtin_amdgcn_s_barrier();
  }
#undef STAGE_HT
#undef RD_A
#undef RD_B
#undef QUAD

  // --- epilogue: bias + bf16, wave-private LDS repack, coalesced 32B stores ---
  float biasv[4];
#pragma unroll
  for (int ni = 0; ni < 4; ++ni) {
    const int col = n0 + (ni >> 1) * 128 + wc * 32 + (ni & 1) * 16 + lr;
    biasv[ni] = (col < 512) ? b1[col] : 0.0f;
  }
  unsigned short* Ls = &Al[0][0] + wid * 1024;   // 2 KB per wave, wave-private
  const int erow = lane >> 2;                    // 0..15
  const int ec   = (lane & 3) * 16;              // 0,16,32,48
  const unsigned cg = (unsigned)(n0 + (ec < 32 ? wc * 32 + ec : 128 + wc * 32 + (ec - 32)));
#pragma unroll
  for (int mi = 0; mi < 8; ++mi) {
#pragma unroll
    for (int ni = 0; ni < 4; ++ni) {
      const int lc = (ni >> 1) * 32 + (ni & 1) * 16 + lr;
#pragma unroll
      for (int r = 0; r < 4; ++r)
        Ls[(g * 4 + r) * 64 + lc] = f2bf(acc[mi][ni][r] + biasv[ni]);
    }
    asm volatile("s_waitcnt lgkmcnt(0)" ::: "memory");   // wave-synchronous repack
    const int grow = m0 + (mi >> 2) * 128 + wr * 64 + (mi & 3) * 16 + erow;
    if (grow < M) {
      const short8 v0 = *(const short8*)&Ls[erow * 64 + ec];
      const short8 v1 = *(const short8*)&Ls[erow * 64 + ec + 8];
      *(short8*)(P + (size_t)grow * 1024 + cg)     = v0;
      *(short8*)(P + (size_t)grow * 1024 + cg + 8) = v1;
    }
    asm volatile("s_waitcnt lgkmcnt(0)" ::: "memory");   // reads done before next overwrite
  }
}

// ---------- kernel 4: per-edge score ----------
__global__ void __launch_bounds__(256) edge_kernel(const unsigned short* __restrict__ P,
                                                   const int* __restrict__ src,
                                                   const int* __restrict__ dst,
                                                   const float* __restrict__ W2,
                                                   const float* __restrict__ b2,
                                                   float* __restrict__ out,
                                                   int E) {
  const int gw   = (blockIdx.x * 256 + threadIdx.x) >> 6;   // global wave = edge
  const int lane = threadIdx.x & 63;
  if (gw >= E) return;
  const int s = src[gw];
  const int d = dst[gw];
  const short8 va = *(const short8*)(P + (size_t)s * 1024 + lane * 8);
  const short8 vb = *(const short8*)(P + (size_t)d * 1024 + 512 + lane * 8);
  const float4 w0 = *(const float4*)(W2 + lane * 8);
  const float4 w1 = *(const float4*)(W2 + lane * 8 + 4);
  float a = 0.f, x;
  x = bf2f((unsigned short)va[0]) + bf2f((unsigned short)vb[0]); a += fmaxf(x, 0.f) * w0.x;
  x = bf2f((unsigned short)va[1]) + bf2f((unsigned short)vb[1]); a += fmaxf(x, 0.f) * w0.y;
  x = bf2f((unsigned short)va[2]) + bf2f((unsigned short)vb[2]); a += fmaxf(x, 0.f) * w0.z;
  x = bf2f((unsigned short)va[3]) + bf2f((unsigned short)vb[3]); a += fmaxf(x, 0.f) * w0.w;
  x = bf2f((unsigned short)va[4]) + bf2f((unsigned short)vb[4]); a += fmaxf(x, 0.f) * w1.x;
  x = bf2f((unsigned short)va[5]) + bf2f((unsigned short)vb[5]); a += fmaxf(x, 0.f) * w1.y;
  x = bf2f((unsigned short)va[6]) + bf2f((unsigned short)vb[6]); a += fmaxf(x, 0.f) * w1.z;
  x = bf2f((unsigned short)va[7]) + bf2f((unsigned short)vb[7]); a += fmaxf(x, 0.f) * w1.w;
#pragma unroll
  for (int o = 32; o > 0; o >>= 1) a += __shfl_down(a, o);
  if (lane == 0) out[gw] = a + b2[0];
}

// ---------- launcher ----------
extern "C" void kernel_launch(void* const* d_in, const int* in_sizes, int n_in,
                              void* d_out, int out_size, void* d_ws, size_t ws_size,
                              hipStream_t stream) {
  const float* h  = (const float*)d_in[0];
  const int*   src = (const int*)d_in[1];
  const int*   dst = (const int*)d_in[2];
  const float* W1 = (const float*)d_in[3];
  const float* b1 = (const float*)d_in[4];
  const float* W2 = (const float*)d_in[5];
  const float* b2 = (const float*)d_in[6];
  float* out = (float*)d_out;

  const int M = in_sizes[0] / 512;   // 100000 nodes
  const int E = in_sizes[1];         // 160000 edges

  char* ws = (char*)d_ws;
  unsigned short* hA = (unsigned short*)ws;                          // M*512 bf16
  size_t off = (((size_t)M * 512 * 2) + 255) & ~(size_t)255;
  unsigned short* BT = (unsigned short*)(ws + off);                  // 1024*512 bf16
  off += (size_t)1024 * 512 * 2;
  unsigned short* P = (unsigned short*)(ws + off);                   // M*1024 bf16

  const long long total8 = (long long)M * 512 / 8;
  cast_h_kernel<<<(int)((total8 + 255) / 256), 256, 0, stream>>>(h, hA, total8);
  buildBT_kernel<<<2048, 256, 0, stream>>>(W1, BT);
  const int Mtiles = (M + 255) / 256;          // 391
  gemm_kernel<<<Mtiles * 4, 512, 0, stream>>>(hA, BT, b1, P, M);
  edge_kernel<<<(E + 3) / 4, 256, 0, stream>>>(P, src, dst, W2, b2, out, E);
}